// Round 2
// baseline (33972.964 us; speedup 1.0000x reference)
//
#include <hip/hip_runtime.h>
#include <math.h>

#define HID   256
#define GATES 1024   // 4*HID
#define BATCH 64
#define SEQ   2048

// ---------------------------------------------------------------------------
// GEMM: out[r][g] = sum_k A_row(r)[k] * W[g][k] + bias[g]   (unchanged, proven)
// ---------------------------------------------------------------------------
#define BM 128
#define BN 128
#define BK 16
#define LDP 132

__global__ __launch_bounds__(256, 2)
void xg_gemm(const float* __restrict__ A, const float* __restrict__ W,
             const float* __restrict__ bias, float* __restrict__ out,
             int a_bstride, int ch_log2)
{
    __shared__ float As[BK][LDP];
    __shared__ float Ws[BK][LDP];

    const int tid   = threadIdx.x;
    const int m_blk = blockIdx.x * BM;
    const int n_blk = blockIdx.y * BN;

    const int tn = (tid & 15) * 4;
    const int tm = (tid >> 4) * 4;

    float acc[8][8];
    #pragma unroll
    for (int i = 0; i < 8; ++i)
        #pragma unroll
        for (int j = 0; j < 8; ++j) acc[i][j] = 0.f;

    const int lrow = tid >> 2;
    const int lkc  = (tid & 3) * 4;
    const int CHm1 = (1 << ch_log2) - 1;

    for (int k0 = 0; k0 < HID; k0 += BK) {
        #pragma unroll
        for (int p = 0; p < 2; ++p) {
            int row = p * 64 + lrow;
            int r   = m_blk + row;
            int b   = r >> ch_log2;
            int t   = r & CHm1;
            const float4 a = *(const float4*)(A + (size_t)b * a_bstride +
                                              (size_t)t * HID + k0 + lkc);
            As[lkc + 0][row] = a.x;
            As[lkc + 1][row] = a.y;
            As[lkc + 2][row] = a.z;
            As[lkc + 3][row] = a.w;

            int g = n_blk + row;
            const float4 w = *(const float4*)(W + (size_t)g * HID + k0 + lkc);
            Ws[lkc + 0][row] = w.x;
            Ws[lkc + 1][row] = w.y;
            Ws[lkc + 2][row] = w.z;
            Ws[lkc + 3][row] = w.w;
        }
        __syncthreads();

        #pragma unroll
        for (int kk = 0; kk < BK; ++kk) {
            float4 a0 = *(const float4*)&As[kk][tm];
            float4 a1 = *(const float4*)&As[kk][tm + 64];
            float4 b0 = *(const float4*)&Ws[kk][tn];
            float4 b1 = *(const float4*)&Ws[kk][tn + 64];
            float av[8] = {a0.x, a0.y, a0.z, a0.w, a1.x, a1.y, a1.z, a1.w};
            float bv[8] = {b0.x, b0.y, b0.z, b0.w, b1.x, b1.y, b1.z, b1.w};
            #pragma unroll
            for (int i = 0; i < 8; ++i)
                #pragma unroll
                for (int j = 0; j < 8; ++j)
                    acc[i][j] += av[i] * bv[j];
        }
        __syncthreads();
    }

    const float4 bias0 = *(const float4*)&bias[n_blk + tn];
    const float4 bias1 = *(const float4*)&bias[n_blk + tn + 64];
    #pragma unroll
    for (int i = 0; i < 8; ++i) {
        int m  = (i < 4) ? (tm + i) : (tm + 60 + i);
        int gm = m_blk + m;
        float* op = out + (size_t)gm * GATES + n_blk;
        float4 v0 = {acc[i][0] + bias0.x, acc[i][1] + bias0.y,
                     acc[i][2] + bias0.z, acc[i][3] + bias0.w};
        float4 v1 = {acc[i][4] + bias1.x, acc[i][5] + bias1.y,
                     acc[i][6] + bias1.z, acc[i][7] + bias1.w};
        *(float4*)(op + tn)      = v0;
        *(float4*)(op + tn + 64) = v1;
    }
}

// ---------------------------------------------------------------------------
// Fused dual-layer recurrence (v8): layer-1 chunk c (phase A) + layer-2 chunk
// c-1 (phase B) interleaved in one kernel. The two chains are data-independent
// inside the kernel (xg2 for chunk c-1 was GEMMed from h1ch after the previous
// launch); phase B executes in the ~1.3 us mailbox-RT latency shadow of phase
// A, halving the number of sequential mailbox round trips per LSTM step.
//
// 256 wgs x 512 threads (8 waves), 1 wg/CU forced by VGPR(~245)+LDS(141KB).
// Thread (kc=tid&7, u=tid>>3): unit u, gates i,f,g,o, k-range [32kc,32kc+32).
// Weights: w_hh1 4x8 float4 in regs (128); w_hh2 gates i,f in regs (64),
// gates g,o in XOR-swizzled LDS (128KB, conflict-free b128 stream).
// Mailboxes: per-layer (tag<<32|h) parity scheme, unchanged semantics.
// ---------------------------------------------------------------------------
#define MBSTRIDE ((size_t)BATCH * HID)   // ulongs per parity block

__device__ __forceinline__ float sigmoid_f(float x) {
    return 1.f / (1.f + __expf(-x));
}
__device__ __forceinline__ float tanh_f(float x) {
    return 1.f - 2.f / (1.f + __expf(2.f * x));
}
__device__ __forceinline__ float dot4(float4 a, float4 b) {
    return a.x * b.x + a.y * b.y + a.z * b.z + a.w * b.w;
}

__global__ __launch_bounds__(512, 2)
void lstm_rec_fused(const float* __restrict__ xg1, const float* __restrict__ xg2,
                    const float* __restrict__ w_hh, const float* __restrict__ b_hh,
                    unsigned long long* mb1, unsigned long long* mb2,
                    float* __restrict__ cs1, float* __restrict__ cs2,
                    float* __restrict__ h1ch,
                    int CH, int gbaseA, int gbaseB, int doA, int doB)
{
    // h staged per 32-float chunk padded to 36 (bank spread, 16B-aligned rows)
    __shared__ __attribute__((aligned(16))) float h1sh[8 * 36];
    __shared__ __attribute__((aligned(16))) float h2sh[8 * 36];
    // partials: part[kc][4u+j] = gate j of unit u, k-chunk kc
    __shared__ __attribute__((aligned(16))) float part[8][260];
    // w_hh2 gates g,o: 512 threads x 64 floats, 256B/thread, XOR-swizzled
    __shared__ __attribute__((aligned(16))) float wl[32768];   // 128 KB

    const int s   = blockIdx.x >> 6;
    const int b   = blockIdx.x & 63;
    const int tid = threadIdx.x;
    const int kc  = tid & 7;             // k-chunk of 32
    const int u   = tid >> 3;            // unit 0..63
    const int kq  = kc << 4;             // swizzle term

    // ---- one-time: layer-1 w_hh slice, 4 gates x 8 float4, laundered ----
    float4 w1[4][8];
    #pragma unroll
    for (int g = 0; g < 4; ++g) {
        const float* wr = w_hh + (size_t)(g * 256 + s * 64 + u) * HID + kc * 32;
        #pragma unroll
        for (int i = 0; i < 8; ++i) {
            float4 w = *(const float4*)(wr + 4 * i);
            asm volatile("" : "+v"(w.x), "+v"(w.y), "+v"(w.z), "+v"(w.w));
            w1[g][i] = w;
        }
    }
    // ---- one-time: layer-2 w_hh gates 0,1 (i,f) in regs ----
    const float* whh2 = w_hh + (size_t)GATES * HID;
    float4 w2[2][8];
    #pragma unroll
    for (int g = 0; g < 2; ++g) {
        const float* wr = whh2 + (size_t)(g * 256 + s * 64 + u) * HID + kc * 32;
        #pragma unroll
        for (int i = 0; i < 8; ++i) {
            float4 w = *(const float4*)(wr + 4 * i);
            asm volatile("" : "+v"(w.x), "+v"(w.y), "+v"(w.z), "+v"(w.w));
            w2[g][i] = w;
        }
    }
    // ---- one-time: layer-2 w_hh gates 2,3 (g,o) into swizzled LDS ----
    char* wlb = (char*)wl + tid * 256;
    #pragma unroll
    for (int g2 = 0; g2 < 2; ++g2) {
        const float* wr = whh2 + (size_t)((2 + g2) * 256 + s * 64 + u) * HID + kc * 32;
        #pragma unroll
        for (int i = 0; i < 8; ++i) {
            float4 w = *(const float4*)(wr + 4 * i);
            int m = g2 * 8 + i;
            *(float4*)(wlb + ((m * 16) ^ kq)) = w;
        }
    }
    // no barrier needed: wl rows are thread-private (write==read owner)

    // ---- one-time: owner state & biases (ownerA wave 0, ownerB wave 1) ----
    const int guA = s * 64 + tid;        // valid tid<64
    const int u2  = tid - 64;
    const int guB = s * 64 + u2;         // valid 64<=tid<128
    float c1 = 0.f, c2 = 0.f;
    float bhA[4] = {0.f, 0.f, 0.f, 0.f};
    float bhB[4] = {0.f, 0.f, 0.f, 0.f};
    if (tid < 64) {
        if (doA) c1 = cs1[b * HID + guA];
        #pragma unroll
        for (int g = 0; g < 4; ++g) bhA[g] = b_hh[g * 256 + guA];
    } else if (tid < 128) {
        if (doB) c2 = cs2[b * HID + guB];
        #pragma unroll
        for (int g = 0; g < 4; ++g) bhB[g] = b_hh[GATES + g * 256 + guB];
    }

    const float* xg1_b = xg1 + (size_t)b * CH * GATES;
    const float* xg2_b = xg2 + (size_t)b * CH * GATES;

    for (int t = 0; t < CH; ++t) {
        const int gtA = gbaseA + t;
        const int gtB = gbaseB + t;

        // ---- owners: prefetch xg before the spin ----
        float xvA[4], xvB[4];
        if (doA && tid < 64) {
            const float* xp = xg1_b + (size_t)t * GATES;
            #pragma unroll
            for (int g = 0; g < 4; ++g) xvA[g] = xp[g * 256 + guA];
        }
        if (doB && tid >= 64 && tid < 128) {
            const float* xp = xg2_b + (size_t)t * GATES;
            #pragma unroll
            for (int g = 0; g < 4; ++g) xvB[g] = xp[g * 256 + guB];
        }

        // ---- stage: waves 0-3 poll mb1 -> h1sh; waves 4-7 poll mb2 -> h2sh --
        if (doA && tid < 256) {
            const unsigned long long* slot =
                mb1 + (size_t)(gtA & 1) * MBSTRIDE + b * HID + tid;
            unsigned long long w;
            do {
                w = __hip_atomic_load(slot, __ATOMIC_RELAXED,
                                      __HIP_MEMORY_SCOPE_AGENT);
            } while ((unsigned)(w >> 32) != (unsigned)gtA);
            h1sh[(tid >> 5) * 36 + (tid & 31)] = __uint_as_float((unsigned)w);
        }
        if (doB && tid >= 256) {
            const int j = tid - 256;
            const unsigned long long* slot =
                mb2 + (size_t)(gtB & 1) * MBSTRIDE + b * HID + j;
            unsigned long long w;
            do {
                w = __hip_atomic_load(slot, __ATOMIC_RELAXED,
                                      __HIP_MEMORY_SCOPE_AGENT);
            } while ((unsigned)(w >> 32) != (unsigned)gtB);
            h2sh[(j >> 5) * 36 + (j & 31)] = __uint_as_float((unsigned)w);
        }
        __syncthreads();   // bar1: h1sh/h2sh ready

        // ---- phase A matvec: layer-1 w_hh @ h1(t-1) ----
        if (doA) {
            const float4* hq = (const float4*)&h1sh[kc * 36];
            float4 hh[8];
            #pragma unroll
            for (int i = 0; i < 8; ++i) hh[i] = hq[i];
            float4 pv;
            float* pp = (float*)&pv;
            #pragma unroll
            for (int g = 0; g < 4; ++g) {
                float a = 0.f;
                #pragma unroll
                for (int i = 0; i < 8; ++i) a += dot4(w1[g][i], hh[i]);
                pp[g] = a;
            }
            *(float4*)&part[kc][4 * u] = pv;
        }
        __syncthreads();   // bar2: partials A ready

        // ---- ownersA: reduce, cell update, publish h1(t) ----
        if (doA && tid < 64) {
            float gx = 0.f, gy = 0.f, gz = 0.f, gw = 0.f;
            #pragma unroll
            for (int k = 0; k < 8; ++k) {
                float4 pk = *(const float4*)&part[k][4 * tid];
                gx += pk.x; gy += pk.y; gz += pk.z; gw += pk.w;
            }
            float ig = sigmoid_f(gx + xvA[0] + bhA[0]);
            float fg = sigmoid_f(gy + xvA[1] + bhA[1]);
            float gv = tanh_f   (gz + xvA[2] + bhA[2]);
            float og = sigmoid_f(gw + xvA[3] + bhA[3]);
            c1 = fg * c1 + ig * gv;
            float h = og * tanh_f(c1);
            __hip_atomic_store(
                mb1 + (size_t)((gtA + 1) & 1) * MBSTRIDE + b * HID + guA,
                ((unsigned long long)(unsigned)(gtA + 1) << 32) |
                    (unsigned long long)__float_as_uint(h),
                __ATOMIC_RELAXED, __HIP_MEMORY_SCOPE_AGENT);
            h1ch[((size_t)b * CH + t) * HID + guA] = h;
        }
        __syncthreads();   // bar3: part free for phase B

        // ---- phase B matvec: layer-2 w_hh @ h2(t'-1) (regs + LDS stream) ----
        if (doB) {
            const float4* hq = (const float4*)&h2sh[kc * 36];
            float4 hh[8];
            #pragma unroll
            for (int i = 0; i < 8; ++i) hh[i] = hq[i];
            float p0 = 0.f, p1 = 0.f, p2 = 0.f, p3 = 0.f;
            #pragma unroll
            for (int i = 0; i < 8; ++i) {
                p0 += dot4(w2[0][i], hh[i]);
                p1 += dot4(w2[1][i], hh[i]);
            }
            #pragma unroll
            for (int m = 0; m < 16; ++m) {
                float4 wv = *(const float4*)(wlb + ((m * 16) ^ kq));
                float d = dot4(wv, hh[m & 7]);
                if (m < 8) p2 += d; else p3 += d;
            }
            float4 pv = {p0, p1, p2, p3};
            *(float4*)&part[kc][4 * u] = pv;
        }
        __syncthreads();   // bar4: partials B ready

        // ---- ownersB: reduce, cell update, publish h2(t') ----
        if (doB && tid >= 64 && tid < 128) {
            float gx = 0.f, gy = 0.f, gz = 0.f, gw = 0.f;
            #pragma unroll
            for (int k = 0; k < 8; ++k) {
                float4 pk = *(const float4*)&part[k][4 * u2];
                gx += pk.x; gy += pk.y; gz += pk.z; gw += pk.w;
            }
            float ig = sigmoid_f(gx + xvB[0] + bhB[0]);
            float fg = sigmoid_f(gy + xvB[1] + bhB[1]);
            float gv = tanh_f   (gz + xvB[2] + bhB[2]);
            float og = sigmoid_f(gw + xvB[3] + bhB[3]);
            c2 = fg * c2 + ig * gv;
            float h = og * tanh_f(c2);
            __hip_atomic_store(
                mb2 + (size_t)((gtB + 1) & 1) * MBSTRIDE + b * HID + guB,
                ((unsigned long long)(unsigned)(gtB + 1) << 32) |
                    (unsigned long long)__float_as_uint(h),
                __ATOMIC_RELAXED, __HIP_MEMORY_SCOPE_AGENT);
        }
        // no bar5: next-iter stage writes (h1sh/h2sh) occur after bar4; part
        // rewrites occur after next bar1, which ownersB reach post-publish.
    }

    if (doA && tid < 64)                cs1[b * HID + guA] = c1;
    if (doB && tid >= 64 && tid < 128)  cs2[b * HID + guB] = c2;
}

// ---------------------------------------------------------------------------
__global__ void final_linear(const unsigned long long* __restrict__ hw,
                             const float* __restrict__ w_lin,
                             const float* __restrict__ b_lin,
                             float* __restrict__ out)
{
    int b = blockIdx.x;
    int l = threadIdx.x;
    float p = 0.f;
    #pragma unroll
    for (int j = 0; j < 4; ++j) {
        int u = l + j * 64;
        p += __uint_as_float((unsigned)hw[b * HID + u]) * w_lin[u];
    }
    #pragma unroll
    for (int off = 32; off > 0; off >>= 1) p += __shfl_down(p, off, 64);
    if (l == 0) out[b] = p + b_lin[0];
}

// ---------------------------------------------------------------------------
extern "C" void kernel_launch(void* const* d_in, const int* in_sizes, int n_in,
                              void* d_out, int out_size, void* d_ws, size_t ws_size,
                              hipStream_t stream)
{
    const float* input = (const float*)d_in[0];
    const float* w_ih  = (const float*)d_in[1];
    const float* w_hh  = (const float*)d_in[2];
    const float* b_ih  = (const float*)d_in[3];
    const float* b_hh  = (const float*)d_in[4];
    const float* w_lin = (const float*)d_in[5];
    const float* b_lin = (const float*)d_in[6];
    float* out = (float*)d_out;

    const size_t c_elems  = (size_t)BATCH * HID;
    const size_t mb_bytes = 2 * MBSTRIDE * sizeof(unsigned long long);
    char*  ws   = (char*)d_ws;
    float* cs1  = (float*)ws;
    float* cs2  = cs1 + c_elems;
    unsigned long long* mb1 = (unsigned long long*)(cs2 + c_elems);
    unsigned long long* mb2 = mb1 + 2 * MBSTRIDE;
    const size_t zero_bytes = 2 * c_elems * 4 + 2 * mb_bytes;
    float* big  = (float*)(ws + ((zero_bytes + 255) & ~(size_t)255));

    int CH = 256;   // fit-checked; falls back if ws_size is smaller
    while (CH > 16) {
        size_t need = ((zero_bytes + 255) & ~(size_t)255)
                    + ((size_t)2 * BATCH * CH * GATES + (size_t)BATCH * CH * HID) * 4;
        if (need <= ws_size) break;
        CH >>= 1;
    }
    const int ch_log2 = __builtin_ctz((unsigned)CH);

    float* xg1  = big;
    float* xg2  = xg1 + (size_t)BATCH * CH * GATES;
    float* h1ch = xg2 + (size_t)BATCH * CH * GATES;

    hipMemsetAsync(ws, 0, zero_bytes, stream);

    const int NC = SEQ / CH;
    dim3 gblk(BATCH * CH / BM, GATES / BN);

    // chunk-lag pipeline: launch c runs layer-1 on chunk c and layer-2 on
    // chunk c-1; GEMM2(c-1) consumes h1ch written by the previous launch.
    for (int c = 0; c <= NC; ++c) {
        if (c < NC)
            xg_gemm<<<gblk, 256, 0, stream>>>(input + (size_t)c * CH * HID, w_ih,
                                              b_ih, xg1, SEQ * HID, ch_log2);
        if (c >= 1)
            xg_gemm<<<gblk, 256, 0, stream>>>(h1ch, w_ih + (size_t)GATES * HID,
                                              b_ih + GATES, xg2, CH * HID, ch_log2);
        lstm_rec_fused<<<256, 512, 0, stream>>>(xg1, xg2, w_hh, b_hh, mb1, mb2,
                                                cs1, cs2, h1ch, CH,
                                                c * CH, (c - 1) * CH,
                                                (c < NC) ? 1 : 0, (c >= 1) ? 1 : 0);
    }

    // last h2 (step 2047, tag 2048) sits in mb2 parity-0 block
    final_linear<<<BATCH, 64, 0, stream>>>(mb2, w_lin, b_lin, out);
}

// Round 3
// 33224.686 us; speedup vs baseline: 1.0225x; 1.0225x over previous
//
#include <hip/hip_runtime.h>
#include <math.h>

#define HID   256
#define GATES 1024   // 4*HID
#define BATCH 64
#define SEQ   2048

// ---------------------------------------------------------------------------
// GEMM: out[r][g] = sum_k A_row(r)[k] * W[g][k] + bias[g]   (unchanged, proven)
// ---------------------------------------------------------------------------
#define BM 128
#define BN 128
#define BK 16
#define LDP 132

__global__ __launch_bounds__(256, 2)
void xg_gemm(const float* __restrict__ A, const float* __restrict__ W,
             const float* __restrict__ bias, float* __restrict__ out,
             int a_bstride, int ch_log2)
{
    __shared__ float As[BK][LDP];
    __shared__ float Ws[BK][LDP];

    const int tid   = threadIdx.x;
    const int m_blk = blockIdx.x * BM;
    const int n_blk = blockIdx.y * BN;

    const int tn = (tid & 15) * 4;
    const int tm = (tid >> 4) * 4;

    float acc[8][8];
    #pragma unroll
    for (int i = 0; i < 8; ++i)
        #pragma unroll
        for (int j = 0; j < 8; ++j) acc[i][j] = 0.f;

    const int lrow = tid >> 2;
    const int lkc  = (tid & 3) * 4;
    const int CHm1 = (1 << ch_log2) - 1;

    for (int k0 = 0; k0 < HID; k0 += BK) {
        #pragma unroll
        for (int p = 0; p < 2; ++p) {
            int row = p * 64 + lrow;
            int r   = m_blk + row;
            int b   = r >> ch_log2;
            int t   = r & CHm1;
            const float4 a = *(const float4*)(A + (size_t)b * a_bstride +
                                              (size_t)t * HID + k0 + lkc);
            As[lkc + 0][row] = a.x;
            As[lkc + 1][row] = a.y;
            As[lkc + 2][row] = a.z;
            As[lkc + 3][row] = a.w;

            int g = n_blk + row;
            const float4 w = *(const float4*)(W + (size_t)g * HID + k0 + lkc);
            Ws[lkc + 0][row] = w.x;
            Ws[lkc + 1][row] = w.y;
            Ws[lkc + 2][row] = w.z;
            Ws[lkc + 3][row] = w.w;
        }
        __syncthreads();

        #pragma unroll
        for (int kk = 0; kk < BK; ++kk) {
            float4 a0 = *(const float4*)&As[kk][tm];
            float4 a1 = *(const float4*)&As[kk][tm + 64];
            float4 b0 = *(const float4*)&Ws[kk][tn];
            float4 b1 = *(const float4*)&Ws[kk][tn + 64];
            float av[8] = {a0.x, a0.y, a0.z, a0.w, a1.x, a1.y, a1.z, a1.w};
            float bv[8] = {b0.x, b0.y, b0.z, b0.w, b1.x, b1.y, b1.z, b1.w};
            #pragma unroll
            for (int i = 0; i < 8; ++i)
                #pragma unroll
                for (int j = 0; j < 8; ++j)
                    acc[i][j] += av[i] * bv[j];
        }
        __syncthreads();
    }

    const float4 bias0 = *(const float4*)&bias[n_blk + tn];
    const float4 bias1 = *(const float4*)&bias[n_blk + tn + 64];
    #pragma unroll
    for (int i = 0; i < 8; ++i) {
        int m  = (i < 4) ? (tm + i) : (tm + 60 + i);
        int gm = m_blk + m;
        float* op = out + (size_t)gm * GATES + n_blk;
        float4 v0 = {acc[i][0] + bias0.x, acc[i][1] + bias0.y,
                     acc[i][2] + bias0.z, acc[i][3] + bias0.w};
        float4 v1 = {acc[i][4] + bias1.x, acc[i][5] + bias1.y,
                     acc[i][6] + bias1.z, acc[i][7] + bias1.w};
        *(float4*)(op + tn)      = v0;
        *(float4*)(op + tn + 64) = v1;
    }
}

// ---------------------------------------------------------------------------
// Recurrence v9: spatial dual-layer + batch-sharing (p=8 batches/wg).
//
// 256 wgs x 1024 threads, 1 wg/CU (80KB dynamic-LDS pad forces it).
// wgs 0..127: layer-1 chunk c. wgs 128..255: layer-2 chunk c-1 (chunk-lag).
// Per wg: slice s (16 units), batch group bg (8 batches).
// Per-step weight stream per wg: 16u x 4g x 256k x 4B = 64KB from L1/L2
// (v7 was 256KB -> its 1.68us/step was L2-BW-bound; this cuts it 4x and
// covers BOTH layers per wall-step). Weights broadcast-coalesce across the
// 8 bq lanes that share each address. No register pinning (r2 lesson:
// pinning -> 128-cap spill -> 5.7GB/dispatch scratch traffic).
// Matvec thread (bq=tid&7, kc=(tid>>3)&7, u=tid>>6): gates i,f,g,o of unit
// u, batch b0+bq, k-range [32kc,32kc+32). Partials in LDS; owner threads
// (tid<128 -> (bq,u)) reduce 8 chunks, cell-update, publish to mailbox.
// Mailbox: (tag<<32|h) parity scheme, agent-scope relaxed (unchanged).
// 2 barriers/step; single-buffered hsh is safe: stage(t+1) writes occur
// only after bar2(t), matvec reads end at bar2(t); part(t+1) writes occur
// after bar1(t+1), owner part(t) reads end before it reaches bar1(t+1).
// ---------------------------------------------------------------------------
#define MBSTRIDE ((size_t)BATCH * HID)   // ulongs per parity block

__device__ __forceinline__ float sigmoid_f(float x) {
    return 1.f / (1.f + __expf(-x));
}
__device__ __forceinline__ float tanh_f(float x) {
    return 1.f - 2.f / (1.f + __expf(2.f * x));
}
__device__ __forceinline__ float dot4(float4 a, float4 b) {
    return a.x * b.x + a.y * b.y + a.z * b.z + a.w * b.w;
}

#define HROW 292   // 8 chunks x 36 + 4 (float4-aligned, bank-spread)
#define PROW 36    // 8 kc x float4 + pad (float4-aligned)

__global__ __launch_bounds__(1024)
void lstm_rec_v9(const float* __restrict__ xg1, const float* __restrict__ xg2,
                 const float* __restrict__ w_hh, const float* __restrict__ b_hh,
                 unsigned long long* mb1, unsigned long long* mb2,
                 float* __restrict__ cs1, float* __restrict__ cs2,
                 float* __restrict__ h1ch,
                 int CH, int gbaseA, int gbaseB, int doA, int doB)
{
    extern __shared__ float dyn_pad[];   // 80KB occupancy limiter (1 wg/CU)
    __shared__ __attribute__((aligned(16))) float hsh[8 * HROW];
    __shared__ __attribute__((aligned(16))) float part[128 * PROW];

    const int bid   = blockIdx.x;
    const int layer = bid >> 7;
    if (layer == 0 && !doA) return;
    if (layer == 1 && !doB) return;
    if (CH < 0) dyn_pad[threadIdx.x] = 1.f;   // keep dyn alloc (never runs)

    const int lid = bid & 127;
    const int s   = lid & 15;            // slice: units [s*16, s*16+16)
    const int b0  = (lid >> 4) * 8;      // batches [b0, b0+8)
    const int tid = threadIdx.x;

    const float* xgL = layer ? xg2 : xg1;
    const float* wL  = w_hh + (size_t)layer * GATES * HID;
    const float* bL  = b_hh + layer * GATES;
    unsigned long long* mbL = layer ? mb2 : mb1;
    float* csL = layer ? cs2 : cs1;
    const int gbase = layer ? gbaseB : gbaseA;

    // matvec identity
    const int bq_m = tid & 7;
    const int kc_m = (tid >> 3) & 7;
    const int u_m  = tid >> 6;           // 0..15
    const int gu_m = s * 16 + u_m;

    // poll identity: 2 slots (8 batches x 256 hid = 2048 slots / 1024 thr)
    const int bq_p  = tid >> 7;          // 0..7
    const int hid_p = tid & 127;         // polls hid_p and hid_p+128

    // owner identity (tid<128): (bq_o, u_o)
    const int bq_o = tid >> 4;
    const int u_o  = tid & 15;
    const int gu_o = s * 16 + u_o;

    // ---- one-time: owner state & biases ----
    float c_u = 0.f;
    float bh[4] = {0.f, 0.f, 0.f, 0.f};
    if (tid < 128) {
        c_u = csL[(b0 + bq_o) * HID + gu_o];
        #pragma unroll
        for (int g = 0; g < 4; ++g) bh[g] = bL[g * 256 + gu_o];
    }

    for (int t = 0; t < CH; ++t) {
        const int gt = gbase + t;
        const int pr = gt & 1;

        // ---- owners: prefetch xg before the spin ----
        float xv[4];
        if (tid < 128) {
            const float* xp = xgL + ((size_t)(b0 + bq_o) * CH + t) * GATES;
            #pragma unroll
            for (int g = 0; g < 4; ++g) xv[g] = xp[g * 256 + gu_o];
        }

        // ---- poll 2 mailbox slots, stage h(t-1) into LDS ----
        {
            const unsigned long long* base =
                mbL + (size_t)pr * MBSTRIDE + (b0 + bq_p) * HID;
            unsigned long long w0, w1;
            bool d0 = false, d1 = false;
            do {
                if (!d0) {
                    w0 = __hip_atomic_load(base + hid_p, __ATOMIC_RELAXED,
                                           __HIP_MEMORY_SCOPE_AGENT);
                    d0 = ((unsigned)(w0 >> 32) == (unsigned)gt);
                }
                if (!d1) {
                    w1 = __hip_atomic_load(base + hid_p + 128, __ATOMIC_RELAXED,
                                           __HIP_MEMORY_SCOPE_AGENT);
                    d1 = ((unsigned)(w1 >> 32) == (unsigned)gt);
                }
            } while (!(d0 && d1));
            hsh[bq_p * HROW + ((hid_p >> 5) * 36) + (hid_p & 31)] =
                __uint_as_float((unsigned)w0);
            const int h2 = hid_p + 128;
            hsh[bq_p * HROW + ((h2 >> 5) * 36) + (h2 & 31)] =
                __uint_as_float((unsigned)w1);
        }
        __syncthreads();   // bar1: hsh ready (also fences part reuse)

        // ---- matvec: 32 h floats (LDS) x 4 gate rows (streamed weights) ----
        {
            const float4* hq = (const float4*)&hsh[bq_m * HROW + kc_m * 36];
            float4 hh[8];
            #pragma unroll
            for (int i = 0; i < 8; ++i) hh[i] = hq[i];
            float4 pv;
            float* pp = (float*)&pv;
            #pragma unroll
            for (int g = 0; g < 4; ++g) {
                const float4* wp =
                    (const float4*)(wL + (size_t)(g * 256 + gu_m) * HID +
                                    kc_m * 32);
                float a = 0.f;
                #pragma unroll
                for (int i = 0; i < 8; ++i) a += dot4(wp[i], hh[i]);
                pp[g] = a;
            }
            *(float4*)&part[(bq_m * 16 + u_m) * PROW + kc_m * 4] = pv;
        }
        __syncthreads();   // bar2: partials ready

        // ---- owners: reduce 8 chunks, cell update, publish ----
        if (tid < 128) {
            const float* pr_row = &part[(bq_o * 16 + u_o) * PROW];
            float gx = 0.f, gy = 0.f, gz = 0.f, gw = 0.f;
            #pragma unroll
            for (int k = 0; k < 8; ++k) {
                float4 pk = *(const float4*)(pr_row + k * 4);
                gx += pk.x; gy += pk.y; gz += pk.z; gw += pk.w;
            }
            float ig = sigmoid_f(gx + xv[0] + bh[0]);
            float fg = sigmoid_f(gy + xv[1] + bh[1]);
            float gv = tanh_f   (gz + xv[2] + bh[2]);
            float og = sigmoid_f(gw + xv[3] + bh[3]);
            c_u = fg * c_u + ig * gv;
            float h = og * tanh_f(c_u);

            __hip_atomic_store(
                mbL + (size_t)((gt + 1) & 1) * MBSTRIDE + (b0 + bq_o) * HID + gu_o,
                ((unsigned long long)(unsigned)(gt + 1) << 32) |
                    (unsigned long long)__float_as_uint(h),
                __ATOMIC_RELAXED, __HIP_MEMORY_SCOPE_AGENT);

            if (layer == 0)
                h1ch[((size_t)(b0 + bq_o) * CH + t) * HID + gu_o] = h;
        }
        // no bar3: see header comment (2-barrier safety argument).
    }

    if (tid < 128) csL[(b0 + bq_o) * HID + gu_o] = c_u;
}

// ---------------------------------------------------------------------------
__global__ void final_linear(const unsigned long long* __restrict__ hw,
                             const float* __restrict__ w_lin,
                             const float* __restrict__ b_lin,
                             float* __restrict__ out)
{
    int b = blockIdx.x;
    int l = threadIdx.x;
    float p = 0.f;
    #pragma unroll
    for (int j = 0; j < 4; ++j) {
        int u = l + j * 64;
        p += __uint_as_float((unsigned)hw[b * HID + u]) * w_lin[u];
    }
    #pragma unroll
    for (int off = 32; off > 0; off >>= 1) p += __shfl_down(p, off, 64);
    if (l == 0) out[b] = p + b_lin[0];
}

// ---------------------------------------------------------------------------
extern "C" void kernel_launch(void* const* d_in, const int* in_sizes, int n_in,
                              void* d_out, int out_size, void* d_ws, size_t ws_size,
                              hipStream_t stream)
{
    const float* input = (const float*)d_in[0];
    const float* w_ih  = (const float*)d_in[1];
    const float* w_hh  = (const float*)d_in[2];
    const float* b_ih  = (const float*)d_in[3];
    const float* b_hh  = (const float*)d_in[4];
    const float* w_lin = (const float*)d_in[5];
    const float* b_lin = (const float*)d_in[6];
    float* out = (float*)d_out;

    const size_t c_elems  = (size_t)BATCH * HID;
    const size_t mb_bytes = 2 * MBSTRIDE * sizeof(unsigned long long);
    char*  ws   = (char*)d_ws;
    float* cs1  = (float*)ws;
    float* cs2  = cs1 + c_elems;
    unsigned long long* mb1 = (unsigned long long*)(cs2 + c_elems);
    unsigned long long* mb2 = mb1 + 2 * MBSTRIDE;
    const size_t zero_bytes = 2 * c_elems * 4 + 2 * mb_bytes;
    float* big  = (float*)(ws + ((zero_bytes + 255) & ~(size_t)255));

    int CH = 256;   // fit-checked; falls back if ws_size is smaller
    while (CH > 16) {
        size_t need = ((zero_bytes + 255) & ~(size_t)255)
                    + ((size_t)2 * BATCH * CH * GATES + (size_t)BATCH * CH * HID) * 4;
        if (need <= ws_size) break;
        CH >>= 1;
    }
    const int ch_log2 = __builtin_ctz((unsigned)CH);

    float* xg1  = big;
    float* xg2  = xg1 + (size_t)BATCH * CH * GATES;
    float* h1ch = xg2 + (size_t)BATCH * CH * GATES;

    hipMemsetAsync(ws, 0, zero_bytes, stream);

    const int NC = SEQ / CH;
    dim3 gblk(BATCH * CH / BM, GATES / BN);

    // chunk-lag pipeline: dispatch c runs layer-1 on chunk c (wgs 0..127)
    // and layer-2 on chunk c-1 (wgs 128..255) concurrently; GEMM2(c-1)
    // consumes h1ch written by the previous rec dispatch.
    for (int c = 0; c <= NC; ++c) {
        if (c < NC)
            xg_gemm<<<gblk, 256, 0, stream>>>(input + (size_t)c * CH * HID, w_ih,
                                              b_ih, xg1, SEQ * HID, ch_log2);
        if (c >= 1)
            xg_gemm<<<gblk, 256, 0, stream>>>(h1ch, w_ih + (size_t)GATES * HID,
                                              b_ih + GATES, xg2, CH * HID, ch_log2);
        lstm_rec_v9<<<256, 1024, 81920, stream>>>(xg1, xg2, w_hh, b_hh, mb1, mb2,
                                                  cs1, cs2, h1ch, CH,
                                                  c * CH, (c - 1) * CH,
                                                  (c < NC) ? 1 : 0, (c >= 1) ? 1 : 0);
    }

    // last h2 (step 2047, tag 2048) sits in mb2 parity-0 block
    final_linear<<<BATCH, 64, 0, stream>>>(mb2, w_lin, b_lin, out);
}

// Round 4
// 7040.894 us; speedup vs baseline: 4.8251x; 4.7188x over previous
//
#include <hip/hip_runtime.h>
#include <math.h>

#define HID   256
#define GATES 1024   // 4*HID
#define BATCH 64
#define SEQ   2048

// ---------------------------------------------------------------------------
// GEMM: out[r][g] = sum_k A_row(r)[k] * W[g][k] + bias[g]   (unchanged, proven)
// ---------------------------------------------------------------------------
#define BM 128
#define BN 128
#define BK 16
#define LDP 132

__global__ __launch_bounds__(256, 2)
void xg_gemm(const float* __restrict__ A, const float* __restrict__ W,
             const float* __restrict__ bias, float* __restrict__ out,
             int a_bstride, int ch_log2)
{
    __shared__ float As[BK][LDP];
    __shared__ float Ws[BK][LDP];

    const int tid   = threadIdx.x;
    const int m_blk = blockIdx.x * BM;
    const int n_blk = blockIdx.y * BN;

    const int tn = (tid & 15) * 4;
    const int tm = (tid >> 4) * 4;

    float acc[8][8];
    #pragma unroll
    for (int i = 0; i < 8; ++i)
        #pragma unroll
        for (int j = 0; j < 8; ++j) acc[i][j] = 0.f;

    const int lrow = tid >> 2;
    const int lkc  = (tid & 3) * 4;
    const int CHm1 = (1 << ch_log2) - 1;

    for (int k0 = 0; k0 < HID; k0 += BK) {
        #pragma unroll
        for (int p = 0; p < 2; ++p) {
            int row = p * 64 + lrow;
            int r   = m_blk + row;
            int b   = r >> ch_log2;
            int t   = r & CHm1;
            const float4 a = *(const float4*)(A + (size_t)b * a_bstride +
                                              (size_t)t * HID + k0 + lkc);
            As[lkc + 0][row] = a.x;
            As[lkc + 1][row] = a.y;
            As[lkc + 2][row] = a.z;
            As[lkc + 3][row] = a.w;

            int g = n_blk + row;
            const float4 w = *(const float4*)(W + (size_t)g * HID + k0 + lkc);
            Ws[lkc + 0][row] = w.x;
            Ws[lkc + 1][row] = w.y;
            Ws[lkc + 2][row] = w.z;
            Ws[lkc + 3][row] = w.w;
        }
        __syncthreads();

        #pragma unroll
        for (int kk = 0; kk < BK; ++kk) {
            float4 a0 = *(const float4*)&As[kk][tm];
            float4 a1 = *(const float4*)&As[kk][tm + 64];
            float4 b0 = *(const float4*)&Ws[kk][tn];
            float4 b1 = *(const float4*)&Ws[kk][tn + 64];
            float av[8] = {a0.x, a0.y, a0.z, a0.w, a1.x, a1.y, a1.z, a1.w};
            float bv[8] = {b0.x, b0.y, b0.z, b0.w, b1.x, b1.y, b1.z, b1.w};
            #pragma unroll
            for (int i = 0; i < 8; ++i)
                #pragma unroll
                for (int j = 0; j < 8; ++j)
                    acc[i][j] += av[i] * bv[j];
        }
        __syncthreads();
    }

    const float4 bias0 = *(const float4*)&bias[n_blk + tn];
    const float4 bias1 = *(const float4*)&bias[n_blk + tn + 64];
    #pragma unroll
    for (int i = 0; i < 8; ++i) {
        int m  = (i < 4) ? (tm + i) : (tm + 60 + i);
        int gm = m_blk + m;
        float* op = out + (size_t)gm * GATES + n_blk;
        float4 v0 = {acc[i][0] + bias0.x, acc[i][1] + bias0.y,
                     acc[i][2] + bias0.z, acc[i][3] + bias0.w};
        float4 v1 = {acc[i][4] + bias1.x, acc[i][5] + bias1.y,
                     acc[i][6] + bias1.z, acc[i][7] + bias1.w};
        *(float4*)(op + tn)      = v0;
        *(float4*)(op + tn + 64) = v1;
    }
}

// ---------------------------------------------------------------------------
// Recurrence v10 = v7 machinery + batch-pairing + spatial dual-layer.
//
// v7 (proven 1.68us/step): weights PINNED in 64 regs/thread (v9 lesson:
// streaming weights from cache -> 42MB/step HBM thrash, 8x regression);
// thread (kc=tid&15, u=tid>>4) computes gates i,f,g,o of unit u over
// k-range [16kc,16kc+16); parity mailbox (tag<<32|h) agent-scope.
//
// v10 changes: each wg serves TWO batches (b0, b0+1) sequentially per step,
// reusing pinned weights -> 128 wgs/layer; wgs 0..127 run layer-1 chunk c
// while wgs 128..255 run layer-2 chunk c-1 (chunk-lag pipeline, proven in
// r2/r3). Sequential mailbox RTs halve: 4096 -> ~2300; second matvec sits
// in the RT latency shadow. Same 2-barrier scheme as v7 (hsh single-buffer
// now: its t+1 writes happen after bar2(t), matvec(t) reads end at bar2(t);
// part(t+1) writes happen after bar1(t+1), owners read part(t) before it).
// LDS pad forces 1 wg/CU -> deterministic 256-wg co-residency.
// ---------------------------------------------------------------------------
#define MBSTRIDE ((size_t)BATCH * HID)   // ulongs per parity block

__device__ __forceinline__ float sigmoid_f(float x) {
    return 1.f / (1.f + __expf(-x));
}
__device__ __forceinline__ float tanh_f(float x) {
    return 1.f - 2.f / (1.f + __expf(2.f * x));
}

__global__ __launch_bounds__(1024, 4)
void lstm_rec_v10(const float* __restrict__ xg1, const float* __restrict__ xg2,
                  const float* __restrict__ w_hh, const float* __restrict__ b_hh,
                  unsigned long long* mb1, unsigned long long* mb2,
                  float* __restrict__ cs1, float* __restrict__ cs2,
                  float* __restrict__ h1ch,
                  int CH, int gbaseA, int gbaseB, int doA, int doB)
{
    // h(t-1) per batch: 16 chunks of 16 floats padded to 20 (v7 layout)
    __shared__ __attribute__((aligned(16))) float hsh[2][16 * 20];
    // partials per batch: part[bq][kc][4u+j] (260 pad: 16B-aligned rows, v7)
    __shared__ __attribute__((aligned(16))) float part[2][16][260];
    // occupancy limiter: push LDS past 80KB -> exactly 1 wg/CU
    __shared__ float occ_pad[11264];

    const int bid   = blockIdx.x;
    const int layer = bid >> 7;
    if (layer == 0 && !doA) return;
    if (layer == 1 && !doB) return;
    if (CH < 0) occ_pad[threadIdx.x] = 1.f;   // never runs; keeps pad alive

    const int lid = bid & 127;
    const int s   = lid & 3;             // slice: units [s*64, s*64+64)
    const int b0  = (lid >> 2) * 2;      // batches {b0, b0+1}
    const int tid = threadIdx.x;
    const int kc  = tid & 15;            // k-chunk of 16
    const int u   = tid >> 4;            // unit 0..63
    const int gu  = s * 64 + u;

    const float* xgL = layer ? xg2 : xg1;
    const float* wL  = w_hh + (size_t)layer * GATES * HID;
    const float* bL  = b_hh + layer * GATES;
    unsigned long long* mbL = layer ? mb2 : mb1;
    float* csL = layer ? cs2 : cs1;
    const int gbase = layer ? gbaseB : gbaseA;

    // ---- one-time: 4 gate-rows x 16 weights into registers, laundered ----
    float4 wreg[4][4];
    #pragma unroll
    for (int j = 0; j < 4; ++j) {
        const float* wr = wL + (size_t)(j * 256 + gu) * HID + kc * 16;
        #pragma unroll
        for (int i = 0; i < 4; ++i) {
            float4 w = *(const float4*)(wr + 4 * i);
            asm volatile("" : "+v"(w.x), "+v"(w.y), "+v"(w.z), "+v"(w.w));
            wreg[j][i] = w;
        }
    }

    // ---- owner identity (tid<128): batch bq_o, unit u_o ----
    const int bq_o = tid >> 6;           // 0..1
    const int u_o  = tid & 63;
    const int gu_o = s * 64 + u_o;
    float c_u = 0.f;
    float bh[4] = {0.f, 0.f, 0.f, 0.f};
    if (tid < 128) {
        c_u = csL[(b0 + bq_o) * HID + gu_o];
        #pragma unroll
        for (int g = 0; g < 4; ++g) bh[g] = bL[g * 256 + gu_o];
    }

    // ---- poll identity (tid<512): batch bq_p, hid slot ----
    const int bq_p  = tid >> 8;          // 0..1
    const int hid_p = tid & 255;

    for (int t = 0; t < CH; ++t) {
        const int gt = gbase + t;
        const int pr = gt & 1;

        // ---- owners: prefetch xg before the spin ----
        float xv[4];
        if (tid < 128) {
            const float* xp = xgL + ((size_t)(b0 + bq_o) * CH + t) * GATES;
            #pragma unroll
            for (int g = 0; g < 4; ++g) xv[g] = xp[g * 256 + gu_o];
        }

        // ---- poll mailbox (tag==gt), stage h(t-1) for both batches ----
        if (tid < 512) {
            const unsigned long long* slot =
                mbL + (size_t)pr * MBSTRIDE + (b0 + bq_p) * HID + hid_p;
            unsigned long long w;
            do {
                w = __hip_atomic_load(slot, __ATOMIC_RELAXED,
                                      __HIP_MEMORY_SCOPE_AGENT);
            } while ((unsigned)(w >> 32) != (unsigned)gt);
            hsh[bq_p][(hid_p >> 4) * 20 + (hid_p & 15)] =
                __uint_as_float((unsigned)w);
        }
        __syncthreads();   // bar1: hsh ready (also fences part reuse)

        // ---- matvec x2 batches: 16 h floats, reused across 4 gate rows ----
        #pragma unroll
        for (int bq = 0; bq < 2; ++bq) {
            const float4* hq = (const float4*)&hsh[bq][kc * 20];
            float4 h0 = hq[0], h1 = hq[1], h2 = hq[2], h3 = hq[3];
            float4 pv;
            float* pp = (float*)&pv;
            #pragma unroll
            for (int j = 0; j < 4; ++j) {
                float a = wreg[j][0].x * h0.x + wreg[j][0].y * h0.y
                        + wreg[j][0].z * h0.z + wreg[j][0].w * h0.w;
                a += wreg[j][1].x * h1.x + wreg[j][1].y * h1.y
                   + wreg[j][1].z * h1.z + wreg[j][1].w * h1.w;
                a += wreg[j][2].x * h2.x + wreg[j][2].y * h2.y
                   + wreg[j][2].z * h2.z + wreg[j][2].w * h2.w;
                a += wreg[j][3].x * h3.x + wreg[j][3].y * h3.y
                   + wreg[j][3].z * h3.z + wreg[j][3].w * h3.w;
                pp[j] = a;
            }
            *(float4*)&part[bq][kc][4 * u] = pv;
        }
        __syncthreads();   // bar2: partials ready

        // ---- owners: reduce 16 chunks, cell update, publish ----
        if (tid < 128) {
            float gx = 0.f, gy = 0.f, gz = 0.f, gw = 0.f;
            #pragma unroll
            for (int k = 0; k < 16; ++k) {
                float4 pk = *(const float4*)&part[bq_o][k][4 * u_o];
                gx += pk.x; gy += pk.y; gz += pk.z; gw += pk.w;
            }
            float ig = sigmoid_f(gx + xv[0] + bh[0]);
            float fg = sigmoid_f(gy + xv[1] + bh[1]);
            float gv = tanh_f   (gz + xv[2] + bh[2]);
            float og = sigmoid_f(gw + xv[3] + bh[3]);
            c_u = fg * c_u + ig * gv;
            float h = og * tanh_f(c_u);

            __hip_atomic_store(
                mbL + (size_t)((gt + 1) & 1) * MBSTRIDE + (b0 + bq_o) * HID + gu_o,
                ((unsigned long long)(unsigned)(gt + 1) << 32) |
                    (unsigned long long)__float_as_uint(h),
                __ATOMIC_RELAXED, __HIP_MEMORY_SCOPE_AGENT);

            if (layer == 0)
                h1ch[((size_t)(b0 + bq_o) * CH + t) * HID + gu_o] = h;
        }
        // no bar3: part(t+1) writes happen after bar1(t+1), which owners
        // reach only after finishing part(t) reads; hsh(t+1) writes happen
        // after bar2(t), after all matvec(t) reads.
    }

    if (tid < 128) csL[(b0 + bq_o) * HID + gu_o] = c_u;
}

// ---------------------------------------------------------------------------
__global__ void final_linear(const unsigned long long* __restrict__ hw,
                             const float* __restrict__ w_lin,
                             const float* __restrict__ b_lin,
                             float* __restrict__ out)
{
    int b = blockIdx.x;
    int l = threadIdx.x;
    float p = 0.f;
    #pragma unroll
    for (int j = 0; j < 4; ++j) {
        int u = l + j * 64;
        p += __uint_as_float((unsigned)hw[b * HID + u]) * w_lin[u];
    }
    #pragma unroll
    for (int off = 32; off > 0; off >>= 1) p += __shfl_down(p, off, 64);
    if (l == 0) out[b] = p + b_lin[0];
}

// ---------------------------------------------------------------------------
extern "C" void kernel_launch(void* const* d_in, const int* in_sizes, int n_in,
                              void* d_out, int out_size, void* d_ws, size_t ws_size,
                              hipStream_t stream)
{
    const float* input = (const float*)d_in[0];
    const float* w_ih  = (const float*)d_in[1];
    const float* w_hh  = (const float*)d_in[2];
    const float* b_ih  = (const float*)d_in[3];
    const float* b_hh  = (const float*)d_in[4];
    const float* w_lin = (const float*)d_in[5];
    const float* b_lin = (const float*)d_in[6];
    float* out = (float*)d_out;

    const size_t c_elems  = (size_t)BATCH * HID;
    const size_t mb_bytes = 2 * MBSTRIDE * sizeof(unsigned long long);
    char*  ws   = (char*)d_ws;
    float* cs1  = (float*)ws;
    float* cs2  = cs1 + c_elems;
    unsigned long long* mb1 = (unsigned long long*)(cs2 + c_elems);
    unsigned long long* mb2 = mb1 + 2 * MBSTRIDE;
    const size_t zero_bytes = 2 * c_elems * 4 + 2 * mb_bytes;
    float* big  = (float*)(ws + ((zero_bytes + 255) & ~(size_t)255));

    int CH = 256;   // fit-checked; falls back if ws_size is smaller
    while (CH > 16) {
        size_t need = ((zero_bytes + 255) & ~(size_t)255)
                    + ((size_t)2 * BATCH * CH * GATES + (size_t)BATCH * CH * HID) * 4;
        if (need <= ws_size) break;
        CH >>= 1;
    }
    const int ch_log2 = __builtin_ctz((unsigned)CH);

    float* xg1  = big;
    float* xg2  = xg1 + (size_t)BATCH * CH * GATES;
    float* h1ch = xg2 + (size_t)BATCH * CH * GATES;

    hipMemsetAsync(ws, 0, zero_bytes, stream);

    const int NC = SEQ / CH;
    dim3 gblk(BATCH * CH / BM, GATES / BN);

    // chunk-lag pipeline: dispatch c runs layer-1 on chunk c (wgs 0..127)
    // and layer-2 on chunk c-1 (wgs 128..255) concurrently; GEMM2(c-1)
    // consumes h1ch written by the previous rec dispatch.
    for (int c = 0; c <= NC; ++c) {
        if (c < NC)
            xg_gemm<<<gblk, 256, 0, stream>>>(input + (size_t)c * CH * HID, w_ih,
                                              b_ih, xg1, SEQ * HID, ch_log2);
        if (c >= 1)
            xg_gemm<<<gblk, 256, 0, stream>>>(h1ch, w_ih + (size_t)GATES * HID,
                                              b_ih + GATES, xg2, CH * HID, ch_log2);
        lstm_rec_v10<<<256, 1024, 0, stream>>>(xg1, xg2, w_hh, b_hh, mb1, mb2,
                                               cs1, cs2, h1ch, CH,
                                               c * CH, (c - 1) * CH,
                                               (c < NC) ? 1 : 0, (c >= 1) ? 1 : 0);
    }

    // last h2 (step 2047, tag 2048) sits in mb2 parity-0 block
    final_linear<<<BATCH, 64, 0, stream>>>(mb2, w_lin, b_lin, out);
}

// Round 5
// 6085.436 us; speedup vs baseline: 5.5827x; 1.1570x over previous
//
#include <hip/hip_runtime.h>
#include <math.h>

#define HID   256
#define GATES 1024   // 4*HID
#define BATCH 64
#define SEQ   2048

// ---------------------------------------------------------------------------
// GEMM: out[r][g] = sum_k A_row(r)[k] * W[g][k] + bias[g]   (unchanged, proven)
// ---------------------------------------------------------------------------
#define BM 128
#define BN 128
#define BK 16
#define LDP 132

__global__ __launch_bounds__(256, 2)
void xg_gemm(const float* __restrict__ A, const float* __restrict__ W,
             const float* __restrict__ bias, float* __restrict__ out,
             int a_bstride, int ch_log2)
{
    __shared__ float As[BK][LDP];
    __shared__ float Ws[BK][LDP];

    const int tid   = threadIdx.x;
    const int m_blk = blockIdx.x * BM;
    const int n_blk = blockIdx.y * BN;

    const int tn = (tid & 15) * 4;
    const int tm = (tid >> 4) * 4;

    float acc[8][8];
    #pragma unroll
    for (int i = 0; i < 8; ++i)
        #pragma unroll
        for (int j = 0; j < 8; ++j) acc[i][j] = 0.f;

    const int lrow = tid >> 2;
    const int lkc  = (tid & 3) * 4;
    const int CHm1 = (1 << ch_log2) - 1;

    for (int k0 = 0; k0 < HID; k0 += BK) {
        #pragma unroll
        for (int p = 0; p < 2; ++p) {
            int row = p * 64 + lrow;
            int r   = m_blk + row;
            int b   = r >> ch_log2;
            int t   = r & CHm1;
            const float4 a = *(const float4*)(A + (size_t)b * a_bstride +
                                              (size_t)t * HID + k0 + lkc);
            As[lkc + 0][row] = a.x;
            As[lkc + 1][row] = a.y;
            As[lkc + 2][row] = a.z;
            As[lkc + 3][row] = a.w;

            int g = n_blk + row;
            const float4 w = *(const float4*)(W + (size_t)g * HID + k0 + lkc);
            Ws[lkc + 0][row] = w.x;
            Ws[lkc + 1][row] = w.y;
            Ws[lkc + 2][row] = w.z;
            Ws[lkc + 3][row] = w.w;
        }
        __syncthreads();

        #pragma unroll
        for (int kk = 0; kk < BK; ++kk) {
            float4 a0 = *(const float4*)&As[kk][tm];
            float4 a1 = *(const float4*)&As[kk][tm + 64];
            float4 b0 = *(const float4*)&Ws[kk][tn];
            float4 b1 = *(const float4*)&Ws[kk][tn + 64];
            float av[8] = {a0.x, a0.y, a0.z, a0.w, a1.x, a1.y, a1.z, a1.w};
            float bv[8] = {b0.x, b0.y, b0.z, b0.w, b1.x, b1.y, b1.z, b1.w};
            #pragma unroll
            for (int i = 0; i < 8; ++i)
                #pragma unroll
                for (int j = 0; j < 8; ++j)
                    acc[i][j] += av[i] * bv[j];
        }
        __syncthreads();
    }

    const float4 bias0 = *(const float4*)&bias[n_blk + tn];
    const float4 bias1 = *(const float4*)&bias[n_blk + tn + 64];
    #pragma unroll
    for (int i = 0; i < 8; ++i) {
        int m  = (i < 4) ? (tm + i) : (tm + 60 + i);
        int gm = m_blk + m;
        float* op = out + (size_t)gm * GATES + n_blk;
        float4 v0 = {acc[i][0] + bias0.x, acc[i][1] + bias0.y,
                     acc[i][2] + bias0.z, acc[i][3] + bias0.w};
        float4 v1 = {acc[i][4] + bias1.x, acc[i][5] + bias1.y,
                     acc[i][6] + bias1.z, acc[i][7] + bias1.w};
        *(float4*)(op + tn)      = v0;
        *(float4*)(op + tn + 64) = v1;
    }
}

// ---------------------------------------------------------------------------
// Recurrence v11 = v10 + 2-phase batch pipelining (4 barriers/cycle).
//
// v10 cycle (2.42us) = RT + compute(2 batches) serial. v11 staggers the two
// batches' polls/publishes by half a cycle so each chain sees one RT/cycle
// while the OTHER batch's matvec+reduce runs inside that RT:
//   S1: w1-owner finishes b1(t-1) [reduce part1, publish]; pollers poll b0(t)
//   barA
//   S2: all matvec b0 -> part0
//   barB
//   S3: w0-owner reduces part0, publishes b0(t); pollers poll b1(t)
//   barC
//   S4: all matvec b1 -> part1
//   barD  -> next cycle
// Race audit: part0 read in S3(t), next write S2(t+1) after barA(t+1) - w0
// finishes reads before barC(t) < barA(t+1). part1 read in S1(t+1), next
// write S4(t+1) after barC(t+1). hsh0 written S1 (pre-barA), read S2; next
// write after barD(t). hsh1 written S3, read S4; next write after barB(t+1).
// Owners: wave0 = batch b0, wave1 = batch b0+1 (64 thr each). Pollers =
// waves 12-15 (256 thr) so owner work overlaps the other phase's poll.
// LDS pad (volatile-protected vs DCE - v10's pad was eliminated!) pushes
// LDS to 82KB -> hard 1 wg/CU.
// ---------------------------------------------------------------------------
#define MBSTRIDE ((size_t)BATCH * HID)   // ulongs per parity block

__device__ __forceinline__ float sigmoid_f(float x) {
    return 1.f / (1.f + __expf(-x));
}
__device__ __forceinline__ float tanh_f(float x) {
    return 1.f - 2.f / (1.f + __expf(2.f * x));
}

__global__ __launch_bounds__(1024, 4)
void lstm_rec_v11(const float* __restrict__ xg1, const float* __restrict__ xg2,
                  const float* __restrict__ w_hh, const float* __restrict__ b_hh,
                  unsigned long long* mb1, unsigned long long* mb2,
                  float* __restrict__ cs1, float* __restrict__ cs2,
                  float* __restrict__ h1ch,
                  int CH, int gbaseA, int gbaseB, int doA, int doB)
{
    // h(t-1) per phase: 16 chunks of 16 floats padded to 20 (v7 layout)
    __shared__ __attribute__((aligned(16))) float hsh[2][16 * 20];
    // partials double-buffered per phase: part[ph][kc][4u+j]
    __shared__ __attribute__((aligned(16))) float part[2][16][260];
    // occupancy limiter -> 82432B total -> exactly 1 wg/CU
    __shared__ float occ_pad[3328];

    const int bid   = blockIdx.x;
    const int layer = bid >> 7;
    if (layer == 0 && !doA) return;
    if (layer == 1 && !doB) return;

    // keep occ_pad alive: runtime-unprovable guard + volatile accesses
    if (gbaseA == 0x7fffffff) {
        volatile float* vp = occ_pad;
        vp[threadIdx.x] = (float)CH;
        cs1[0] = vp[threadIdx.x ^ 1];
    }

    const int lid = bid & 127;
    const int s   = lid & 3;             // slice: units [s*64, s*64+64)
    const int b0  = (lid >> 2) * 2;      // batches {b0, b0+1}
    const int tid = threadIdx.x;
    const int kc  = tid & 15;            // k-chunk of 16
    const int u   = tid >> 4;            // unit 0..63
    const int gu  = s * 64 + u;

    const float* xgL = layer ? xg2 : xg1;
    const float* wL  = w_hh + (size_t)layer * GATES * HID;
    const float* bL  = b_hh + layer * GATES;
    unsigned long long* mbL = layer ? mb2 : mb1;
    float* csL = layer ? cs2 : cs1;
    const int gbase = layer ? gbaseB : gbaseA;

    // ---- one-time: 4 gate-rows x 16 weights into registers, laundered ----
    float4 wreg[4][4];
    #pragma unroll
    for (int j = 0; j < 4; ++j) {
        const float* wr = wL + (size_t)(j * 256 + gu) * HID + kc * 16;
        #pragma unroll
        for (int i = 0; i < 4; ++i) {
            float4 w = *(const float4*)(wr + 4 * i);
            asm volatile("" : "+v"(w.x), "+v"(w.y), "+v"(w.z), "+v"(w.w));
            wreg[j][i] = w;
        }
    }

    // ---- owner identity: wave0 -> batch b0 (phase 0), wave1 -> b0+1 ----
    const int u_o  = tid & 63;
    const int gu_o = s * 64 + u_o;
    const int b_o  = b0 + ((tid >> 6) & 1);   // valid for tid<128
    float c_u = 0.f;
    float bh[4] = {0.f, 0.f, 0.f, 0.f};
    float xv[4] = {0.f, 0.f, 0.f, 0.f};
    if (tid < 128) {
        c_u = csL[b_o * HID + gu_o];
        #pragma unroll
        for (int g = 0; g < 4; ++g) bh[g] = bL[g * 256 + gu_o];
    }

    // ---- poller identity: waves 12-15, slot pt in [0,256) ----
    const int pt = tid - 768;

    for (int t = 0; t < CH; ++t) {
        const int gt = gbase + t;
        const int pr = gt & 1;

        // ================= S1 =================
        if (tid >= 768) {
            // poll b0 h(t-1), tag gt (published by w0 in S3 of prev cycle)
            const unsigned long long* slot =
                mbL + (size_t)pr * MBSTRIDE + b0 * HID + pt;
            unsigned long long w;
            do {
                w = __hip_atomic_load(slot, __ATOMIC_RELAXED,
                                      __HIP_MEMORY_SCOPE_AGENT);
            } while ((unsigned)(w >> 32) != (unsigned)gt);
            hsh[0][(pt >> 4) * 20 + (pt & 15)] = __uint_as_float((unsigned)w);
        } else if (tid < 128) {
            if ((tid & 64) && t > 0) {
                // w1: finish b1 step t-1: reduce part1, update, publish tag gt
                float gx = 0.f, gy = 0.f, gz = 0.f, gw = 0.f;
                #pragma unroll
                for (int k = 0; k < 16; ++k) {
                    float4 pk = *(const float4*)&part[1][k][4 * u_o];
                    gx += pk.x; gy += pk.y; gz += pk.z; gw += pk.w;
                }
                float ig = sigmoid_f(gx + xv[0] + bh[0]);
                float fg = sigmoid_f(gy + xv[1] + bh[1]);
                float gv = tanh_f   (gz + xv[2] + bh[2]);
                float og = sigmoid_f(gw + xv[3] + bh[3]);
                c_u = fg * c_u + ig * gv;
                float h = og * tanh_f(c_u);
                __hip_atomic_store(
                    mbL + (size_t)(gt & 1) * MBSTRIDE + b_o * HID + gu_o,
                    ((unsigned long long)(unsigned)gt << 32) |
                        (unsigned long long)__float_as_uint(h),
                    __ATOMIC_RELAXED, __HIP_MEMORY_SCOPE_AGENT);
                if (layer == 0)
                    h1ch[((size_t)b_o * CH + (t - 1)) * HID + gu_o] = h;
            }
            // owners (both waves): prefetch xv(t) for own batch
            const float* xp = xgL + ((size_t)b_o * CH + t) * GATES;
            #pragma unroll
            for (int g = 0; g < 4; ++g) xv[g] = xp[g * 256 + gu_o];
        }
        __syncthreads();   // barA: hsh0 ready; part1(t-1) consumed

        // ================= S2: matvec b0 -> part0 =================
        {
            const float4* hq = (const float4*)&hsh[0][kc * 20];
            float4 h0 = hq[0], h1 = hq[1], h2 = hq[2], h3 = hq[3];
            float4 pv;
            float* pp = (float*)&pv;
            #pragma unroll
            for (int j = 0; j < 4; ++j) {
                float a = wreg[j][0].x * h0.x + wreg[j][0].y * h0.y
                        + wreg[j][0].z * h0.z + wreg[j][0].w * h0.w;
                a += wreg[j][1].x * h1.x + wreg[j][1].y * h1.y
                   + wreg[j][1].z * h1.z + wreg[j][1].w * h1.w;
                a += wreg[j][2].x * h2.x + wreg[j][2].y * h2.y
                   + wreg[j][2].z * h2.z + wreg[j][2].w * h2.w;
                a += wreg[j][3].x * h3.x + wreg[j][3].y * h3.y
                   + wreg[j][3].z * h3.z + wreg[j][3].w * h3.w;
                pp[j] = a;
            }
            *(float4*)&part[0][kc][4 * u] = pv;
        }
        __syncthreads();   // barB: part0 ready

        // ================= S3 =================
        if (tid < 64) {
            // w0: finish b0 step t: reduce part0, update, publish tag gt+1
            float gx = 0.f, gy = 0.f, gz = 0.f, gw = 0.f;
            #pragma unroll
            for (int k = 0; k < 16; ++k) {
                float4 pk = *(const float4*)&part[0][k][4 * u_o];
                gx += pk.x; gy += pk.y; gz += pk.z; gw += pk.w;
            }
            float ig = sigmoid_f(gx + xv[0] + bh[0]);
            float fg = sigmoid_f(gy + xv[1] + bh[1]);
            float gv = tanh_f   (gz + xv[2] + bh[2]);
            float og = sigmoid_f(gw + xv[3] + bh[3]);
            c_u = fg * c_u + ig * gv;
            float h = og * tanh_f(c_u);
            __hip_atomic_store(
                mbL + (size_t)((gt + 1) & 1) * MBSTRIDE + b_o * HID + gu_o,
                ((unsigned long long)(unsigned)(gt + 1) << 32) |
                    (unsigned long long)__float_as_uint(h),
                __ATOMIC_RELAXED, __HIP_MEMORY_SCOPE_AGENT);
            if (layer == 0)
                h1ch[((size_t)b_o * CH + t) * HID + gu_o] = h;
        } else if (tid >= 768) {
            // poll b1 h(t-1), tag gt (published by w1 in S1 of THIS cycle)
            const unsigned long long* slot =
                mbL + (size_t)pr * MBSTRIDE + (b0 + 1) * HID + pt;
            unsigned long long w;
            do {
                w = __hip_atomic_load(slot, __ATOMIC_RELAXED,
                                      __HIP_MEMORY_SCOPE_AGENT);
            } while ((unsigned)(w >> 32) != (unsigned)gt);
            hsh[1][(pt >> 4) * 20 + (pt & 15)] = __uint_as_float((unsigned)w);
        }
        __syncthreads();   // barC: hsh1 ready; part0 consumed

        // ================= S4: matvec b1 -> part1 =================
        {
            const float4* hq = (const float4*)&hsh[1][kc * 20];
            float4 h0 = hq[0], h1 = hq[1], h2 = hq[2], h3 = hq[3];
            float4 pv;
            float* pp = (float*)&pv;
            #pragma unroll
            for (int j = 0; j < 4; ++j) {
                float a = wreg[j][0].x * h0.x + wreg[j][0].y * h0.y
                        + wreg[j][0].z * h0.z + wreg[j][0].w * h0.w;
                a += wreg[j][1].x * h1.x + wreg[j][1].y * h1.y
                   + wreg[j][1].z * h1.z + wreg[j][1].w * h1.w;
                a += wreg[j][2].x * h2.x + wreg[j][2].y * h2.y
                   + wreg[j][2].z * h2.z + wreg[j][2].w * h2.w;
                a += wreg[j][3].x * h3.x + wreg[j][3].y * h3.y
                   + wreg[j][3].z * h3.z + wreg[j][3].w * h3.w;
                pp[j] = a;
            }
            *(float4*)&part[1][kc][4 * u] = pv;
        }
        __syncthreads();   // barD: part1 ready -> consumed next S1
    }

    // ---- epilogue: w1 finishes b1 step CH-1 (tag gbase+CH) ----
    if (tid >= 64 && tid < 128) {
        const int gt_e = gbase + CH;
        float gx = 0.f, gy = 0.f, gz = 0.f, gw = 0.f;
        #pragma unroll
        for (int k = 0; k < 16; ++k) {
            float4 pk = *(const float4*)&part[1][k][4 * u_o];
            gx += pk.x; gy += pk.y; gz += pk.z; gw += pk.w;
        }
        float ig = sigmoid_f(gx + xv[0] + bh[0]);
        float fg = sigmoid_f(gy + xv[1] + bh[1]);
        float gv = tanh_f   (gz + xv[2] + bh[2]);
        float og = sigmoid_f(gw + xv[3] + bh[3]);
        c_u = fg * c_u + ig * gv;
        float h = og * tanh_f(c_u);
        __hip_atomic_store(
            mbL + (size_t)(gt_e & 1) * MBSTRIDE + b_o * HID + gu_o,
            ((unsigned long long)(unsigned)gt_e << 32) |
                (unsigned long long)__float_as_uint(h),
            __ATOMIC_RELAXED, __HIP_MEMORY_SCOPE_AGENT);
        if (layer == 0)
            h1ch[((size_t)b_o * CH + (CH - 1)) * HID + gu_o] = h;
    }

    if (tid < 128) csL[b_o * HID + gu_o] = c_u;
}

// ---------------------------------------------------------------------------
__global__ void final_linear(const unsigned long long* __restrict__ hw,
                             const float* __restrict__ w_lin,
                             const float* __restrict__ b_lin,
                             float* __restrict__ out)
{
    int b = blockIdx.x;
    int l = threadIdx.x;
    float p = 0.f;
    #pragma unroll
    for (int j = 0; j < 4; ++j) {
        int u = l + j * 64;
        p += __uint_as_float((unsigned)hw[b * HID + u]) * w_lin[u];
    }
    #pragma unroll
    for (int off = 32; off > 0; off >>= 1) p += __shfl_down(p, off, 64);
    if (l == 0) out[b] = p + b_lin[0];
}

// ---------------------------------------------------------------------------
extern "C" void kernel_launch(void* const* d_in, const int* in_sizes, int n_in,
                              void* d_out, int out_size, void* d_ws, size_t ws_size,
                              hipStream_t stream)
{
    const float* input = (const float*)d_in[0];
    const float* w_ih  = (const float*)d_in[1];
    const float* w_hh  = (const float*)d_in[2];
    const float* b_ih  = (const float*)d_in[3];
    const float* b_hh  = (const float*)d_in[4];
    const float* w_lin = (const float*)d_in[5];
    const float* b_lin = (const float*)d_in[6];
    float* out = (float*)d_out;

    const size_t c_elems  = (size_t)BATCH * HID;
    const size_t mb_bytes = 2 * MBSTRIDE * sizeof(unsigned long long);
    char*  ws   = (char*)d_ws;
    float* cs1  = (float*)ws;
    float* cs2  = cs1 + c_elems;
    unsigned long long* mb1 = (unsigned long long*)(cs2 + c_elems);
    unsigned long long* mb2 = mb1 + 2 * MBSTRIDE;
    const size_t zero_bytes = 2 * c_elems * 4 + 2 * mb_bytes;
    float* big  = (float*)(ws + ((zero_bytes + 255) & ~(size_t)255));

    int CH = 256;   // fit-checked; falls back if ws_size is smaller
    while (CH > 16) {
        size_t need = ((zero_bytes + 255) & ~(size_t)255)
                    + ((size_t)2 * BATCH * CH * GATES + (size_t)BATCH * CH * HID) * 4;
        if (need <= ws_size) break;
        CH >>= 1;
    }
    const int ch_log2 = __builtin_ctz((unsigned)CH);

    float* xg1  = big;
    float* xg2  = xg1 + (size_t)BATCH * CH * GATES;
    float* h1ch = xg2 + (size_t)BATCH * CH * GATES;

    hipMemsetAsync(ws, 0, zero_bytes, stream);

    const int NC = SEQ / CH;
    dim3 gblk(BATCH * CH / BM, GATES / BN);

    // chunk-lag pipeline: dispatch c runs layer-1 on chunk c (wgs 0..127)
    // and layer-2 on chunk c-1 (wgs 128..255) concurrently; GEMM2(c-1)
    // consumes h1ch written by the previous rec dispatch.
    for (int c = 0; c <= NC; ++c) {
        if (c < NC)
            xg_gemm<<<gblk, 256, 0, stream>>>(input + (size_t)c * CH * HID, w_ih,
                                              b_ih, xg1, SEQ * HID, ch_log2);
        if (c >= 1)
            xg_gemm<<<gblk, 256, 0, stream>>>(h1ch, w_ih + (size_t)GATES * HID,
                                              b_ih + GATES, xg2, CH * HID, ch_log2);
        lstm_rec_v11<<<256, 1024, 0, stream>>>(xg1, xg2, w_hh, b_hh, mb1, mb2,
                                               cs1, cs2, h1ch, CH,
                                               c * CH, (c - 1) * CH,
                                               (c < NC) ? 1 : 0, (c >= 1) ? 1 : 0);
    }

    // last h2 (step 2047, tag 2048) sits in mb2 parity-0 block
    final_linear<<<BATCH, 64, 0, stream>>>(mb2, w_lin, b_lin, out);
}